// Round 17
// baseline (2976.450 us; speedup 1.0000x reference)
//
#include <hip/hip_runtime.h>

// Problem constants: B=8, N=16384, NPOINT=1024, NSAMPLE=32, RADIUS=0.4, C_IN=64
#define R2 0.16f  // f32-nearest of python 0.4*0.4 (== nearest f32 to 0.16)

typedef float f32x2 __attribute__((ext_vector_type(2)));

// Exact (non-contracted) squared distance for ball query.
__device__ __forceinline__ float sqd(float x, float y, float z,
                                     float px, float py, float pz) {
  float dx = __fsub_rn(x, px);
  float dy = __fsub_rn(y, py);
  float dz = __fsub_rn(z, pz);
  return __fadd_rn(__fadd_rn(__fmul_rn(dx, dx), __fmul_rn(dy, dy)),
                   __fmul_rn(dz, dz));
}

// Canonical gfx9 wave64 reduce via DPP (verified R12-R16). Valid in lane 63.
__device__ __forceinline__ float wave64_max_dpp(float x) {
#define DPP_STEP(CTRL)                                                      \
  {                                                                         \
    int t_ = __builtin_amdgcn_update_dpp(__float_as_int(x),                 \
                                         __float_as_int(x), CTRL, 0xf, 0xf, \
                                         false);                            \
    x = fmaxf(x, __int_as_float(t_));                                       \
  }
  DPP_STEP(0x111) DPP_STEP(0x112) DPP_STEP(0x114)
  DPP_STEP(0x118) DPP_STEP(0x142) DPP_STEP(0x143)
#undef DPP_STEP
  return x;
}
__device__ __forceinline__ unsigned wave64_min_dpp_u32(unsigned x) {
#define DPP_STEP(CTRL)                                                      \
  {                                                                         \
    unsigned t_ = (unsigned)__builtin_amdgcn_update_dpp(                    \
        (int)x, (int)x, CTRL, 0xf, 0xf, false);                             \
    x = (t_ < x) ? t_ : x;                                                  \
  }
  DPP_STEP(0x111) DPP_STEP(0x112) DPP_STEP(0x114)
  DPP_STEP(0x118) DPP_STEP(0x142) DPP_STEP(0x143)
#undef DPP_STEP
  return x;
}

// ---------------- counting sort by 8x8x8 grid cell (per batch) ---------------
__global__ __launch_bounds__(256) void zero_hist(unsigned* __restrict__ h) {
  h[blockIdx.x * 256 + threadIdx.x] = 0u;  // grid 16 -> 4096 entries
}

__global__ __launch_bounds__(256) void hist_kernel(const float* __restrict__ xyz,
                                                   unsigned* __restrict__ hist,
                                                   unsigned* __restrict__ rank,
                                                   unsigned* __restrict__ cid) {
  int t = blockIdx.x * 256 + threadIdx.x;  // 0..131071 = (b,n)
  int b = t >> 14;
  const float* p = xyz + (size_t)t * 3;
  int cx = (int)floorf(p[0] + 4.0f);
  int cy = (int)floorf(p[1] + 4.0f);
  int cz = (int)floorf(p[2] + 4.0f);
  cx = min(max(cx, 0), 7);
  cy = min(max(cy, 0), 7);
  cz = min(max(cz, 0), 7);
  unsigned c = (unsigned)(cx | (cy << 3) | (cz << 6));
  unsigned r = atomicAdd(&hist[(b << 9) + c], 1u);
  rank[t] = r;
  cid[t] = c;
}

__global__ __launch_bounds__(512) void scan_kernel(const unsigned* __restrict__ hist,
                                                   unsigned* __restrict__ starts) {
  __shared__ unsigned a[512];
  int b = blockIdx.x, t = threadIdx.x;
  unsigned h = hist[(b << 9) + t];
  a[t] = h;
  __syncthreads();
  for (int s = 1; s < 512; s <<= 1) {
    unsigned v = (t >= s) ? a[t - s] : 0u;
    __syncthreads();
    a[t] += v;
    __syncthreads();
  }
  starts[(b << 9) + t] = a[t] - h;  // exclusive
}

__global__ __launch_bounds__(256) void scatter_kernel(
    const float* __restrict__ xyz, const unsigned* __restrict__ starts,
    const unsigned* __restrict__ rank, const unsigned* __restrict__ cid,
    float* __restrict__ xs2, float* __restrict__ ys2, float* __restrict__ zs2,
    unsigned* __restrict__ oi2) {
  int t = blockIdx.x * 256 + threadIdx.x;
  int b = t >> 14, n = t & 16383;
  unsigned pos = starts[(b << 9) + cid[t]] + rank[t];
  const float* p = xyz + (size_t)t * 3;
  size_t o = ((size_t)b << 14) + pos;
  xs2[o] = p[0];
  ys2[o] = p[1];
  zs2[o] = p[2];
  oi2[o] = (unsigned)n;
}

// ---------------- FPS: one block (512 thr, 8 waves) per batch ----------------
// 32 SORTED pts/thread. R16 post-mortem: sweep ~450 cyc/iter, fixed machinery
// ~3800 — so halve the wave count (issue serialization + barrier) and shrink
// the reduce chain. Per iteration:
//   per-thread bbox skip (R16-proven, exact: d2>=lb>=tv>=min_d) -> sweep only
//   if needed; DPP val max -> readlane(63); rare lanes (tv==bvf) rescan regs
//   for min ORIG idx + capture coords (xylds reads + Z regs); DPP u32 min;
//   the unique lane with coi==woi writes coords to s_cd[sl][wid] and
//   atomicMax's packed key into s_gkey[sl]:
//     key = (valbits<<17) | ((16383-oi)<<3) | wid   (49 bits)
//   u64 max == lexicographic (max val, min orig idx); wid tag is consistent
//   (oi unique -> one candidate per (val,oi)). ONE barrier; post-barrier:
//   one u64 read -> decode wid/j -> 3 coord reads. No L2 coord load, no
//   shuffle butterfly. s_gkey/s_cd 3-slot rotation, s_gkey reset 2-ahead
//   post-barrier (writers of slot (it+2)%3 are after barrier(it+1); readers
//   of its old value finished before barrier(it-2..); epoch-safe).
// x,y in LDS thread-private slots; z,M in regs (if the allocator remats Z
// from zs, the cost lands only in the ~10% non-skipped sweeps - acceptable).
__global__ __launch_bounds__(512) void fps_kernel(
    const float* __restrict__ xyz, const float* __restrict__ xs,
    const float* __restrict__ ys, const float* __restrict__ zs,
    const unsigned* __restrict__ oi, int* __restrict__ idx_out) {
#pragma clang fp contract(off)
  extern __shared__ float4 xylds[];  // 8192 entries = 128 KB
  __shared__ unsigned long long s_gkey[3];
  __shared__ float s_cd[3][3][8];
  int b = blockIdx.x;
  int tid = threadIdx.x;
  int lane = tid & 63, wid = tid >> 6;
  const float* xb = xyz + (size_t)b * 16384 * 3;
  int base = tid << 5;  // 32 consecutive sorted slots
  const float4* xv = (const float4*)(xs + ((size_t)b << 14) + base);
  const float4* yv = (const float4*)(ys + ((size_t)b << 14) + base);
  const float4* zv = (const float4*)(zs + ((size_t)b << 14) + base);
  const uint4* ov = (const uint4*)(oi + ((size_t)b << 14) + base);
  float xr[32], yr[32], zr[32];
  unsigned OI[32];
#pragma unroll
  for (int q = 0; q < 8; ++q) {
    *(float4*)(xr + 4 * q) = xv[q];
    *(float4*)(yr + 4 * q) = yv[q];
    *(float4*)(zr + 4 * q) = zv[q];
    *(uint4*)(OI + 4 * q) = ov[q];
  }
  // per-thread bbox of its 32 points
  float bxl = xr[0], bxh = xr[0], byl = yr[0], byh = yr[0], bzl = zr[0],
        bzh = zr[0];
#pragma unroll
  for (int k = 1; k < 32; ++k) {
    bxl = fminf(bxl, xr[k]); bxh = fmaxf(bxh, xr[k]);
    byl = fminf(byl, yr[k]); byh = fmaxf(byh, yr[k]);
    bzl = fminf(bzl, zr[k]); bzh = fmaxf(bzh, zr[k]);
  }
  f32x2 Z[16], M[16];
#pragma unroll
  for (int q = 0; q < 16; ++q) {
    xylds[(q << 9) + tid] =
        make_float4(xr[2 * q], xr[2 * q + 1], yr[2 * q], yr[2 * q + 1]);
    Z[q] = {zr[2 * q], zr[2 * q + 1]};
    M[q] = {__builtin_inff(), __builtin_inff()};
  }
  if (tid == 0) idx_out[b * 1024] = 0;
  if (tid < 3) s_gkey[tid] = 0ull;
  __syncthreads();
  float px = xb[0], py = xb[1], pz = xb[2];
  float tv = __builtin_inff();  // invariant: tv == max(M)
  for (int it = 1; it < 1024; ++it) {
    int sl = it % 3;
    int slp2 = (sl + 2) % 3;
    // ---- bbox skip test (conservative: 0.999 shrink)
    float ddx = fmaxf(fmaxf(bxl - px, px - bxh), 0.0f);
    float ddy = fmaxf(fmaxf(byl - py, py - byh), 0.0f);
    float ddz = fmaxf(fmaxf(bzl - pz, pz - bzh), 0.0f);
    float lb = (ddx * ddx + ddy * ddy + ddz * ddz) * 0.999f;
    if (lb < tv) {
      // ---- packed sweep: native f32x2, no FMA (contract off)
      f32x2 px2 = {px, px}, py2 = {py, py}, pz2 = {pz, pz};
      float ntv = -1.0f;
#pragma unroll
      for (int q = 0; q < 16; ++q) {
        float4 t = xylds[(q << 9) + tid];  // {x0,x1,y0,y1}
        f32x2 X = {t.x, t.y};
        f32x2 Y = {t.z, t.w};
        f32x2 dx = X - px2;
        f32x2 dy = Y - py2;
        f32x2 dz = Z[q] - pz2;
        f32x2 d = dx * dx + dy * dy + dz * dz;  // RN each op, ref order
        M[q].x = fminf(M[q].x, d.x);
        M[q].y = fminf(M[q].y, d.y);
        ntv = fmaxf(fmaxf(ntv, M[q].x), M[q].y);
      }
      tv = ntv;
    }
    // ---- wave candidate: DPP value max, rare lanes rescan (min OI + coords)
    float bv = wave64_max_dpp(tv);
    unsigned bvb = (unsigned)__builtin_amdgcn_readlane(__float_as_int(bv), 63);
    float bvf = __int_as_float((int)bvb);
    unsigned coi = 0xffffffffu;
    float wx = 0.0f, wy = 0.0f, wz = 0.0f;
    if (tv == bvf) {  // >=1 lane per wave; register+private-LDS rescan
#pragma unroll
      for (int q = 0; q < 16; ++q) {
        float4 t = xylds[(q << 9) + tid];
        if (M[q].x == bvf && OI[2 * q] < coi) {
          coi = OI[2 * q]; wx = t.x; wy = t.z; wz = Z[q].x;
        }
        if (M[q].y == bvf && OI[2 * q + 1] < coi) {
          coi = OI[2 * q + 1]; wx = t.y; wy = t.w; wz = Z[q].y;
        }
      }
    }
    unsigned woi = wave64_min_dpp_u32(coi);
    if (coi == woi && coi != 0xffffffffu) {  // unique lane (oi unique)
      s_cd[sl][0][wid] = wx;
      s_cd[sl][1][wid] = wy;
      s_cd[sl][2][wid] = wz;
      unsigned long long key = ((unsigned long long)bvb << 17) |
                               ((unsigned long long)(16383u - woi) << 3) |
                               (unsigned long long)wid;
      atomicMax(&s_gkey[sl], key);
    }
    __syncthreads();  // the only barrier
    unsigned long long gk = s_gkey[sl];
    if (tid == 0) s_gkey[slp2] = 0ull;  // reset 2-ahead (epoch-safe)
    int w2 = (int)(gk & 7ull);
    int j = 16383 - (int)((gk >> 3) & 0x3fffull);
    px = s_cd[sl][0][w2];
    py = s_cd[sl][1][w2];
    pz = s_cd[sl][2][w2];
    if (tid == 0) idx_out[b * 1024 + it] = j;
  }
}

// ---------------- gather new_xyz into d_out[0 .. 24576) ----------------------
__global__ __launch_bounds__(256) void gather_newxyz(const float* __restrict__ xyz,
                                                     const int* __restrict__ idx,
                                                     float* __restrict__ out) {
  int t = blockIdx.x * 256 + threadIdx.x;  // 0..8191 = (b,p)
  int b = t >> 10;
  int i = idx[t];
  const float* src = xyz + ((size_t)b * 16384 + i) * 3;
  float* dst = out + (size_t)t * 3;
  dst[0] = src[0];
  dst[1] = src[1];
  dst[2] = src[2];
}

// ---------------- transpose features (B,64,N) -> (B,N,64) --------------------
__global__ __launch_bounds__(256) void transpose_feats(const float* __restrict__ f,
                                                       float* __restrict__ fT) {
  __shared__ float tile[64][65];
  int b = blockIdx.x >> 8;
  int n0 = (blockIdx.x & 255) << 6;
  int t = threadIdx.x;
  int nn = t & 63, c0 = t >> 6;
#pragma unroll
  for (int r = 0; r < 64; r += 4) {
    int c = c0 + r;
    tile[c][nn] = f[((size_t)b * 64 + c) * 16384 + n0 + nn];
  }
  __syncthreads();
  int cc = t & 63, n1 = t >> 6;
#pragma unroll
  for (int r = 0; r < 64; r += 4) {
    int n = n1 + r;
    fT[((size_t)b * 16384 + n0 + n) * 64 + cc] = tile[cc][n];
  }
}

// ---------------- ball query: one wave per centroid --------------------------
__global__ __launch_bounds__(256) void ballquery_kernel(const float* __restrict__ xyz,
                                                        const float* __restrict__ newxyz,
                                                        int* __restrict__ gidx) {
  int wid = threadIdx.x >> 6, lane = threadIdx.x & 63;
  int cid = blockIdx.x * 4 + wid;  // 0..8191
  int b = cid >> 10;
  const float* xb = xyz + (size_t)b * 16384 * 3;
  float cx = newxyz[cid * 3 + 0];
  float cy = newxyz[cid * 3 + 1];
  float cz = newxyz[cid * 3 + 2];
  int* out = gidx + (size_t)cid * 32;
  int found = 0;
  int first = -1;
  for (int c0 = 0; c0 < 16384; c0 += 64) {
    int g = c0 + lane;
    float xx = xb[g * 3 + 0], yy = xb[g * 3 + 1], zz = xb[g * 3 + 2];
    float d2 = sqd(xx, yy, zz, cx, cy, cz);
    bool inr = (d2 <= R2);
    unsigned long long mask = __ballot(inr);
    if (first < 0 && mask) first = c0 + (int)__builtin_ctzll(mask);
    int pre = __popcll(mask & ((1ull << lane) - 1ull));
    int slot = found + pre;
    if (inr && slot < 32) out[slot] = g;
    found += __popcll(mask);
    if (found >= 32) break;
  }
  for (int s = found + lane; s < 32; s += 64) out[s] = first;
}

// ---------------- fused group + MLP(67->64->64->128) + maxpool ---------------
#define FMA16(BASEPTR)                                                     \
  do {                                                                     \
    const float4* hp_ = (const float4*)(BASEPTR);                          \
    float4 v0 = hp_[0], v1 = hp_[1], v2 = hp_[2], v3 = hp_[3];             \
    float a = acc[s];                                                      \
    a = fmaf(w[0], v0.x, a);  a = fmaf(w[1], v0.y, a);                     \
    a = fmaf(w[2], v0.z, a);  a = fmaf(w[3], v0.w, a);                     \
    a = fmaf(w[4], v1.x, a);  a = fmaf(w[5], v1.y, a);                     \
    a = fmaf(w[6], v1.z, a);  a = fmaf(w[7], v1.w, a);                     \
    a = fmaf(w[8], v2.x, a);  a = fmaf(w[9], v2.y, a);                     \
    a = fmaf(w[10], v2.z, a); a = fmaf(w[11], v2.w, a);                    \
    a = fmaf(w[12], v3.x, a); a = fmaf(w[13], v3.y, a);                    \
    a = fmaf(w[14], v3.z, a); a = fmaf(w[15], v3.w, a);                    \
    acc[s] = a;                                                            \
  } while (0)

__global__ __launch_bounds__(256) void mlp_kernel(
    const float* __restrict__ xyz, const float* __restrict__ feats,
    const float* __restrict__ featsT, const float* __restrict__ newxyz,
    const int* __restrict__ gidx,
    const float* __restrict__ W1, const float* __restrict__ b1,
    const float* __restrict__ W2, const float* __restrict__ b2,
    const float* __restrict__ W3, const float* __restrict__ b3,
    float* __restrict__ out, int useT) {
  __shared__ float buf[4][32 * 68];
  int wid = threadIdx.x >> 6, lane = threadIdx.x & 63;
  int cid = blockIdx.x * 4 + wid;
  int b = cid >> 10, p = cid & 1023;
  float* A = buf[wid];
  const int* gi = gidx + (size_t)cid * 32;
  float cx = newxyz[cid * 3 + 0];
  float cy = newxyz[cid * 3 + 1];
  float cz = newxyz[cid * 3 + 2];

  // ---- stage h0
  if (useT) {
    const float4* fT4 = (const float4*)(featsT + (size_t)b * 16384 * 64);
    for (int t = lane; t < 512; t += 64) {
      int s = t >> 4, q = t & 15;
      int g = gi[s];
      float4 v = fT4[(size_t)g * 16 + q];
      *(float4*)(A + s * 68 + q * 4) = v;
    }
  } else {
    const float* fb = feats + (size_t)b * 64 * 16384;
    for (int t = lane; t < 2048; t += 64) {
      int c = t >> 5, s = t & 31;
      int g = gi[s];
      A[s * 68 + c] = fb[(size_t)c * 16384 + g];
    }
  }
  for (int t = lane; t < 96; t += 64) {
    int s = t / 3, c = t - s * 3;
    int g = gi[s];
    float pv = xyz[((size_t)b * 16384 + g) * 3 + c];
    float cv = (c == 0) ? cx : ((c == 1) ? cy : cz);
    A[s * 68 + 64 + c] = __fsub_rn(pv, cv);
  }
  if (lane < 32) A[lane * 68 + 67] = 0.0f;
  __syncthreads();

  int o = lane;
  float acc[32];

  // ---- L1: 67 -> 64
#pragma unroll
  for (int s = 0; s < 32; ++s) acc[s] = b1[o];
  {
    const float* wr = W1 + o * 67;
    for (int cb = 0; cb < 4; ++cb) {
      float w[16];
#pragma unroll
      for (int q = 0; q < 16; ++q) w[q] = wr[3 + cb * 16 + q];
#pragma unroll
      for (int s = 0; s < 32; ++s) { FMA16(A + s * 68 + cb * 16); }
    }
    float w0 = wr[0], w1 = wr[1], w2 = wr[2];
#pragma unroll
    for (int s = 0; s < 32; ++s) {
      float a = acc[s];
      a = fmaf(w0, A[s * 68 + 64], a);
      a = fmaf(w1, A[s * 68 + 65], a);
      a = fmaf(w2, A[s * 68 + 66], a);
      acc[s] = a;
    }
  }
  __syncthreads();
#pragma unroll
  for (int s = 0; s < 32; ++s) A[s * 64 + o] = fmaxf(acc[s], 0.0f);
  __syncthreads();

  // ---- L2: 64 -> 64
#pragma unroll
  for (int s = 0; s < 32; ++s) acc[s] = b2[o];
  {
    const float* wr = W2 + o * 64;
    for (int cb = 0; cb < 4; ++cb) {
      float w[16];
#pragma unroll
      for (int q = 0; q < 16; ++q) w[q] = wr[cb * 16 + q];
#pragma unroll
      for (int s = 0; s < 32; ++s) { FMA16(A + s * 64 + cb * 16); }
    }
  }
  __syncthreads();
#pragma unroll
  for (int s = 0; s < 32; ++s) A[s * 64 + o] = fmaxf(acc[s], 0.0f);
  __syncthreads();

  // ---- L3: 64 -> 128, fused relu + maxpool over s
  float* outp = out + 24576;
  for (int po = 0; po < 2; ++po) {
    int o2 = lane + (po << 6);
#pragma unroll
    for (int s = 0; s < 32; ++s) acc[s] = b3[o2];
    const float* wr = W3 + o2 * 64;
    for (int cb = 0; cb < 4; ++cb) {
      float w[16];
#pragma unroll
      for (int q = 0; q < 16; ++q) w[q] = wr[cb * 16 + q];
#pragma unroll
      for (int s = 0; s < 32; ++s) { FMA16(A + s * 64 + cb * 16); }
    }
    float mx = 0.0f;  // relu floor
#pragma unroll
    for (int s = 0; s < 32; ++s) mx = fmaxf(mx, acc[s]);
    outp[((size_t)b * 128 + o2) * 1024 + p] = mx;
  }
}

extern "C" void kernel_launch(void* const* d_in, const int* in_sizes, int n_in,
                              void* d_out, int out_size, void* d_ws, size_t ws_size,
                              hipStream_t stream) {
  const float* xyz = (const float*)d_in[0];
  const float* feats = (const float*)d_in[1];
  const float* W1 = (const float*)d_in[2];
  const float* b1 = (const float*)d_in[3];
  const float* W2 = (const float*)d_in[4];
  const float* b2 = (const float*)d_in[5];
  const float* W3 = (const float*)d_in[6];
  const float* b3 = (const float*)d_in[7];
  float* out = (float*)d_out;

  // ws layout (bytes):
  char* w = (char*)d_ws;
  int* idx = (int*)w;                              // 32 KB
  int* gidx = (int*)(w + 32768);                   // 1 MB
  unsigned* hist = (unsigned*)(w + 1081344);       // 16 KB (8*512)
  unsigned* starts = (unsigned*)(w + 1097728);     // 16 KB
  unsigned* rank = (unsigned*)(w + 1114112);       // 512 KB
  unsigned* cid = (unsigned*)(w + 1638400);        // 512 KB
  unsigned* oi2 = (unsigned*)(w + 2162688);        // 512 KB
  float* xs2 = (float*)(w + 2686976);              // 512 KB
  float* ys2 = (float*)(w + 3211264);              // 512 KB
  float* zs2 = (float*)(w + 3735552);              // 512 KB
  float* featsT = (float*)(w + 4259840);           // 32 MB (optional)
  size_t needT = 4259840 + (size_t)8 * 16384 * 64 * sizeof(float);
  int useT = (ws_size >= needT) ? 1 : 0;

  zero_hist<<<16, 256, 0, stream>>>(hist);
  hist_kernel<<<512, 256, 0, stream>>>(xyz, hist, rank, cid);
  scan_kernel<<<8, 512, 0, stream>>>(hist, starts);
  scatter_kernel<<<512, 256, 0, stream>>>(xyz, starts, rank, cid, xs2, ys2,
                                          zs2, oi2);
  fps_kernel<<<8, 512, 131072, stream>>>(xyz, xs2, ys2, zs2, oi2, idx);
  gather_newxyz<<<32, 256, 0, stream>>>(xyz, idx, out);
  if (useT) transpose_feats<<<2048, 256, 0, stream>>>(feats, featsT);
  ballquery_kernel<<<2048, 256, 0, stream>>>(xyz, out, gidx);
  mlp_kernel<<<2048, 256, 0, stream>>>(xyz, feats, featsT, out, gidx,
                                       W1, b1, W2, b2, W3, b3, out, useT);
}

// Round 18
// 2070.174 us; speedup vs baseline: 1.4378x; 1.4378x over previous
//
#include <hip/hip_runtime.h>

// Problem constants: B=8, N=16384, NPOINT=1024, NSAMPLE=32, RADIUS=0.4, C_IN=64
#define R2 0.16f  // f32-nearest of python 0.4*0.4 (== nearest f32 to 0.16)

typedef float f32x2 __attribute__((ext_vector_type(2)));

// Exact (non-contracted) squared distance for ball query.
__device__ __forceinline__ float sqd(float x, float y, float z,
                                     float px, float py, float pz) {
  float dx = __fsub_rn(x, px);
  float dy = __fsub_rn(y, py);
  float dz = __fsub_rn(z, pz);
  return __fadd_rn(__fadd_rn(__fmul_rn(dx, dx), __fmul_rn(dy, dy)),
                   __fmul_rn(dz, dz));
}

// Canonical gfx9 wave64 reduce via DPP (verified R12-R17). Valid in lane 63.
__device__ __forceinline__ float wave64_max_dpp(float x) {
#define DPP_STEP(CTRL)                                                      \
  {                                                                         \
    int t_ = __builtin_amdgcn_update_dpp(__float_as_int(x),                 \
                                         __float_as_int(x), CTRL, 0xf, 0xf, \
                                         false);                            \
    x = fmaxf(x, __int_as_float(t_));                                       \
  }
  DPP_STEP(0x111) DPP_STEP(0x112) DPP_STEP(0x114)
  DPP_STEP(0x118) DPP_STEP(0x142) DPP_STEP(0x143)
#undef DPP_STEP
  return x;
}
__device__ __forceinline__ unsigned wave64_min_dpp_u32(unsigned x) {
#define DPP_STEP(CTRL)                                                      \
  {                                                                         \
    unsigned t_ = (unsigned)__builtin_amdgcn_update_dpp(                    \
        (int)x, (int)x, CTRL, 0xf, 0xf, false);                             \
    x = (t_ < x) ? t_ : x;                                                  \
  }
  DPP_STEP(0x111) DPP_STEP(0x112) DPP_STEP(0x114)
  DPP_STEP(0x118) DPP_STEP(0x142) DPP_STEP(0x143)
#undef DPP_STEP
  return x;
}

// ---------------- counting sort by 8x8x8 grid cell (per batch) ---------------
__global__ __launch_bounds__(256) void zero_hist(unsigned* __restrict__ h) {
  h[blockIdx.x * 256 + threadIdx.x] = 0u;  // grid 16 -> 4096 entries
}

__global__ __launch_bounds__(256) void hist_kernel(const float* __restrict__ xyz,
                                                   unsigned* __restrict__ hist,
                                                   unsigned* __restrict__ rank,
                                                   unsigned* __restrict__ cid) {
  int t = blockIdx.x * 256 + threadIdx.x;  // 0..131071 = (b,n)
  int b = t >> 14;
  const float* p = xyz + (size_t)t * 3;
  int cx = (int)floorf(p[0] + 4.0f);
  int cy = (int)floorf(p[1] + 4.0f);
  int cz = (int)floorf(p[2] + 4.0f);
  cx = min(max(cx, 0), 7);
  cy = min(max(cy, 0), 7);
  cz = min(max(cz, 0), 7);
  unsigned c = (unsigned)(cx | (cy << 3) | (cz << 6));
  unsigned r = atomicAdd(&hist[(b << 9) + c], 1u);
  rank[t] = r;
  cid[t] = c;
}

__global__ __launch_bounds__(512) void scan_kernel(const unsigned* __restrict__ hist,
                                                   unsigned* __restrict__ starts) {
  __shared__ unsigned a[512];
  int b = blockIdx.x, t = threadIdx.x;
  unsigned h = hist[(b << 9) + t];
  a[t] = h;
  __syncthreads();
  for (int s = 1; s < 512; s <<= 1) {
    unsigned v = (t >= s) ? a[t - s] : 0u;
    __syncthreads();
    a[t] += v;
    __syncthreads();
  }
  starts[(b << 9) + t] = a[t] - h;  // exclusive
}

__global__ __launch_bounds__(256) void scatter_kernel(
    const float* __restrict__ xyz, const unsigned* __restrict__ starts,
    const unsigned* __restrict__ rank, const unsigned* __restrict__ cid,
    float* __restrict__ xs2, float* __restrict__ ys2, float* __restrict__ zs2,
    unsigned* __restrict__ oi2) {
  int t = blockIdx.x * 256 + threadIdx.x;
  int b = t >> 14, n = t & 16383;
  unsigned pos = starts[(b << 9) + cid[t]] + rank[t];
  const float* p = xyz + (size_t)t * 3;
  size_t o = ((size_t)b << 14) + pos;
  xs2[o] = p[0];
  ys2[o] = p[1];
  zs2[o] = p[2];
  oi2[o] = (unsigned)n;
}

// ---------------- FPS: one block (1024 thr, 16 waves) per batch --------------
// R16 geometry (16 SORTED pts/thread — best measured: 1804 us) + R17's reduce
// protocol (correctness-proven at 8-wave geometry) + monotone rescan
// prefilter. Per iteration:
//   bbox skip (exact: d2>=lb>=tv>=min_d[p]) -> sweep only if lb<tv;
//   DPP val max -> readlane(63) = bvb;
//   PREFILTER: gk0 = relaxed load of s_gkey[sl] (atomicMax is monotone, so a
//     stale read is a lower bound of the final key). Skip the rescan iff
//     bvb < val(gk0): our whole key < gk0 <= final -> our write is a no-op.
//     The winner can never skip (its bvb == final val). Exact.
//   rare lanes rescan regs+private-LDS for min ORIG idx + coords; DPP u32
//   min; unique winning-candidate lane writes coords to s_cd[sl][wid] and
//   atomicMax's key = (valbits<<18)|((16383-oi)<<4)|wid into s_gkey[sl]
//   (u64 lex max == max val, min oi; wid tag unique per (val,oi)).
//   ONE barrier; post-barrier: one b64 read -> decode -> 3 coord LDS reads.
//   No global coord load, no shuffle butterfly.
//   s_gkey/s_cd 3-slot rotation; s_gkey[slp2] reset post-barrier (epoch-safe:
//   writers of slot (it+2)%3 are after barrier(it+1); readers of its old
//   value finished before barrier(it)).
__global__ __launch_bounds__(1024) void fps_kernel(
    const float* __restrict__ xyz, const float* __restrict__ xs,
    const float* __restrict__ ys, const float* __restrict__ zs,
    const unsigned* __restrict__ oi, int* __restrict__ idx_out) {
#pragma clang fp contract(off)
  extern __shared__ float4 xylds[];  // 8192 entries = 128 KB
  __shared__ unsigned long long s_gkey[3];
  __shared__ float s_cd[3][3][16];
  int b = blockIdx.x;
  int tid = threadIdx.x;
  int lane = tid & 63, wid = tid >> 6;
  const float* xb = xyz + (size_t)b * 16384 * 3;
  int base = tid << 4;  // 16 consecutive sorted slots
  const float4* xv = (const float4*)(xs + ((size_t)b << 14) + base);
  const float4* yv = (const float4*)(ys + ((size_t)b << 14) + base);
  const float4* zv = (const float4*)(zs + ((size_t)b << 14) + base);
  const uint4* ov = (const uint4*)(oi + ((size_t)b << 14) + base);
  float xr[16], yr[16], zr[16];
  unsigned OI[16];
#pragma unroll
  for (int q = 0; q < 4; ++q) {
    *(float4*)(xr + 4 * q) = xv[q];
    *(float4*)(yr + 4 * q) = yv[q];
    *(float4*)(zr + 4 * q) = zv[q];
    *(uint4*)(OI + 4 * q) = ov[q];
  }
  // per-thread bbox of its 16 points
  float bxl = xr[0], bxh = xr[0], byl = yr[0], byh = yr[0], bzl = zr[0],
        bzh = zr[0];
#pragma unroll
  for (int k = 1; k < 16; ++k) {
    bxl = fminf(bxl, xr[k]); bxh = fmaxf(bxh, xr[k]);
    byl = fminf(byl, yr[k]); byh = fmaxf(byh, yr[k]);
    bzl = fminf(bzl, zr[k]); bzh = fmaxf(bzh, zr[k]);
  }
  f32x2 Z[8], M[8];
#pragma unroll
  for (int q = 0; q < 8; ++q) {
    xylds[(q << 10) + tid] =
        make_float4(xr[2 * q], xr[2 * q + 1], yr[2 * q], yr[2 * q + 1]);
    Z[q] = {zr[2 * q], zr[2 * q + 1]};
    M[q] = {__builtin_inff(), __builtin_inff()};
  }
  if (tid == 0) idx_out[b * 1024] = 0;
  if (tid < 3) s_gkey[tid] = 0ull;
  __syncthreads();
  float px = xb[0], py = xb[1], pz = xb[2];
  float tv = __builtin_inff();  // invariant: tv == max(M)
  for (int it = 1; it < 1024; ++it) {
    int sl = it % 3;
    int slp2 = (sl + 2) % 3;
    // ---- bbox skip test (conservative: 0.999 shrink)
    float ddx = fmaxf(fmaxf(bxl - px, px - bxh), 0.0f);
    float ddy = fmaxf(fmaxf(byl - py, py - byh), 0.0f);
    float ddz = fmaxf(fmaxf(bzl - pz, pz - bzh), 0.0f);
    float lb = (ddx * ddx + ddy * ddy + ddz * ddz) * 0.999f;
    if (lb < tv) {
      // ---- packed sweep: native f32x2, no FMA (contract off)
      f32x2 px2 = {px, px}, py2 = {py, py}, pz2 = {pz, pz};
      float ntv = -1.0f;
#pragma unroll
      for (int q = 0; q < 8; ++q) {
        float4 t = xylds[(q << 10) + tid];  // {x0,x1,y0,y1}
        f32x2 X = {t.x, t.y};
        f32x2 Y = {t.z, t.w};
        f32x2 dx = X - px2;
        f32x2 dy = Y - py2;
        f32x2 dz = Z[q] - pz2;
        f32x2 d = dx * dx + dy * dy + dz * dz;  // RN each op, ref order
        M[q].x = fminf(M[q].x, d.x);
        M[q].y = fminf(M[q].y, d.y);
        ntv = fmaxf(fmaxf(ntv, M[q].x), M[q].y);
      }
      tv = ntv;
    }
    // ---- wave candidate: DPP value max + monotone prefilter
    float bv = wave64_max_dpp(tv);
    unsigned bvb = (unsigned)__builtin_amdgcn_readlane(__float_as_int(bv), 63);
    float bvf = __int_as_float((int)bvb);
    unsigned long long gk0 = __hip_atomic_load(
        &s_gkey[sl], __ATOMIC_RELAXED, __HIP_MEMORY_SCOPE_WORKGROUP);
    if (bvb >= (unsigned)(gk0 >> 18)) {  // wave might win -> rescan
      unsigned coi = 0xffffffffu;
      float wx = 0.0f, wy = 0.0f, wz = 0.0f;
      if (tv == bvf) {
#pragma unroll
        for (int q = 0; q < 8; ++q) {
          float4 t = xylds[(q << 10) + tid];
          if (M[q].x == bvf && OI[2 * q] < coi) {
            coi = OI[2 * q]; wx = t.x; wy = t.z; wz = Z[q].x;
          }
          if (M[q].y == bvf && OI[2 * q + 1] < coi) {
            coi = OI[2 * q + 1]; wx = t.y; wy = t.w; wz = Z[q].y;
          }
        }
      }
      unsigned woi = wave64_min_dpp_u32(coi);
      if (coi == woi && coi != 0xffffffffu) {  // unique lane (oi unique)
        s_cd[sl][0][wid] = wx;
        s_cd[sl][1][wid] = wy;
        s_cd[sl][2][wid] = wz;
        unsigned long long key = ((unsigned long long)bvb << 18) |
                                 ((unsigned long long)(16383u - woi) << 4) |
                                 (unsigned long long)wid;
        atomicMax(&s_gkey[sl], key);
      }
    }
    __syncthreads();  // the only barrier
    unsigned long long gk = s_gkey[sl];
    if (tid == 0) s_gkey[slp2] = 0ull;  // reset 2-ahead (epoch-safe)
    int w2 = (int)(gk & 15ull);
    int j = 16383 - (int)((gk >> 4) & 0x3fffull);
    px = s_cd[sl][0][w2];
    py = s_cd[sl][1][w2];
    pz = s_cd[sl][2][w2];
    if (tid == 0) idx_out[b * 1024 + it] = j;
  }
}

// ---------------- gather new_xyz into d_out[0 .. 24576) ----------------------
__global__ __launch_bounds__(256) void gather_newxyz(const float* __restrict__ xyz,
                                                     const int* __restrict__ idx,
                                                     float* __restrict__ out) {
  int t = blockIdx.x * 256 + threadIdx.x;  // 0..8191 = (b,p)
  int b = t >> 10;
  int i = idx[t];
  const float* src = xyz + ((size_t)b * 16384 + i) * 3;
  float* dst = out + (size_t)t * 3;
  dst[0] = src[0];
  dst[1] = src[1];
  dst[2] = src[2];
}

// ---------------- transpose features (B,64,N) -> (B,N,64) --------------------
__global__ __launch_bounds__(256) void transpose_feats(const float* __restrict__ f,
                                                       float* __restrict__ fT) {
  __shared__ float tile[64][65];
  int b = blockIdx.x >> 8;
  int n0 = (blockIdx.x & 255) << 6;
  int t = threadIdx.x;
  int nn = t & 63, c0 = t >> 6;
#pragma unroll
  for (int r = 0; r < 64; r += 4) {
    int c = c0 + r;
    tile[c][nn] = f[((size_t)b * 64 + c) * 16384 + n0 + nn];
  }
  __syncthreads();
  int cc = t & 63, n1 = t >> 6;
#pragma unroll
  for (int r = 0; r < 64; r += 4) {
    int n = n1 + r;
    fT[((size_t)b * 16384 + n0 + n) * 64 + cc] = tile[cc][n];
  }
}

// ---------------- ball query: one wave per centroid --------------------------
__global__ __launch_bounds__(256) void ballquery_kernel(const float* __restrict__ xyz,
                                                        const float* __restrict__ newxyz,
                                                        int* __restrict__ gidx) {
  int wid = threadIdx.x >> 6, lane = threadIdx.x & 63;
  int cid = blockIdx.x * 4 + wid;  // 0..8191
  int b = cid >> 10;
  const float* xb = xyz + (size_t)b * 16384 * 3;
  float cx = newxyz[cid * 3 + 0];
  float cy = newxyz[cid * 3 + 1];
  float cz = newxyz[cid * 3 + 2];
  int* out = gidx + (size_t)cid * 32;
  int found = 0;
  int first = -1;
  for (int c0 = 0; c0 < 16384; c0 += 64) {
    int g = c0 + lane;
    float xx = xb[g * 3 + 0], yy = xb[g * 3 + 1], zz = xb[g * 3 + 2];
    float d2 = sqd(xx, yy, zz, cx, cy, cz);
    bool inr = (d2 <= R2);
    unsigned long long mask = __ballot(inr);
    if (first < 0 && mask) first = c0 + (int)__builtin_ctzll(mask);
    int pre = __popcll(mask & ((1ull << lane) - 1ull));
    int slot = found + pre;
    if (inr && slot < 32) out[slot] = g;
    found += __popcll(mask);
    if (found >= 32) break;
  }
  for (int s = found + lane; s < 32; s += 64) out[s] = first;
}

// ---------------- fused group + MLP(67->64->64->128) + maxpool ---------------
#define FMA16(BASEPTR)                                                     \
  do {                                                                     \
    const float4* hp_ = (const float4*)(BASEPTR);                          \
    float4 v0 = hp_[0], v1 = hp_[1], v2 = hp_[2], v3 = hp_[3];             \
    float a = acc[s];                                                      \
    a = fmaf(w[0], v0.x, a);  a = fmaf(w[1], v0.y, a);                     \
    a = fmaf(w[2], v0.z, a);  a = fmaf(w[3], v0.w, a);                     \
    a = fmaf(w[4], v1.x, a);  a = fmaf(w[5], v1.y, a);                     \
    a = fmaf(w[6], v1.z, a);  a = fmaf(w[7], v1.w, a);                     \
    a = fmaf(w[8], v2.x, a);  a = fmaf(w[9], v2.y, a);                     \
    a = fmaf(w[10], v2.z, a); a = fmaf(w[11], v2.w, a);                    \
    a = fmaf(w[12], v3.x, a); a = fmaf(w[13], v3.y, a);                    \
    a = fmaf(w[14], v3.z, a); a = fmaf(w[15], v3.w, a);                    \
    acc[s] = a;                                                            \
  } while (0)

__global__ __launch_bounds__(256) void mlp_kernel(
    const float* __restrict__ xyz, const float* __restrict__ feats,
    const float* __restrict__ featsT, const float* __restrict__ newxyz,
    const int* __restrict__ gidx,
    const float* __restrict__ W1, const float* __restrict__ b1,
    const float* __restrict__ W2, const float* __restrict__ b2,
    const float* __restrict__ W3, const float* __restrict__ b3,
    float* __restrict__ out, int useT) {
  __shared__ float buf[4][32 * 68];
  int wid = threadIdx.x >> 6, lane = threadIdx.x & 63;
  int cid = blockIdx.x * 4 + wid;
  int b = cid >> 10, p = cid & 1023;
  float* A = buf[wid];
  const int* gi = gidx + (size_t)cid * 32;
  float cx = newxyz[cid * 3 + 0];
  float cy = newxyz[cid * 3 + 1];
  float cz = newxyz[cid * 3 + 2];

  // ---- stage h0
  if (useT) {
    const float4* fT4 = (const float4*)(featsT + (size_t)b * 16384 * 64);
    for (int t = lane; t < 512; t += 64) {
      int s = t >> 4, q = t & 15;
      int g = gi[s];
      float4 v = fT4[(size_t)g * 16 + q];
      *(float4*)(A + s * 68 + q * 4) = v;
    }
  } else {
    const float* fb = feats + (size_t)b * 64 * 16384;
    for (int t = lane; t < 2048; t += 64) {
      int c = t >> 5, s = t & 31;
      int g = gi[s];
      A[s * 68 + c] = fb[(size_t)c * 16384 + g];
    }
  }
  for (int t = lane; t < 96; t += 64) {
    int s = t / 3, c = t - s * 3;
    int g = gi[s];
    float pv = xyz[((size_t)b * 16384 + g) * 3 + c];
    float cv = (c == 0) ? cx : ((c == 1) ? cy : cz);
    A[s * 68 + 64 + c] = __fsub_rn(pv, cv);
  }
  if (lane < 32) A[lane * 68 + 67] = 0.0f;
  __syncthreads();

  int o = lane;
  float acc[32];

  // ---- L1: 67 -> 64
#pragma unroll
  for (int s = 0; s < 32; ++s) acc[s] = b1[o];
  {
    const float* wr = W1 + o * 67;
    for (int cb = 0; cb < 4; ++cb) {
      float w[16];
#pragma unroll
      for (int q = 0; q < 16; ++q) w[q] = wr[3 + cb * 16 + q];
#pragma unroll
      for (int s = 0; s < 32; ++s) { FMA16(A + s * 68 + cb * 16); }
    }
    float w0 = wr[0], w1 = wr[1], w2 = wr[2];
#pragma unroll
    for (int s = 0; s < 32; ++s) {
      float a = acc[s];
      a = fmaf(w0, A[s * 68 + 64], a);
      a = fmaf(w1, A[s * 68 + 65], a);
      a = fmaf(w2, A[s * 68 + 66], a);
      acc[s] = a;
    }
  }
  __syncthreads();
#pragma unroll
  for (int s = 0; s < 32; ++s) A[s * 64 + o] = fmaxf(acc[s], 0.0f);
  __syncthreads();

  // ---- L2: 64 -> 64
#pragma unroll
  for (int s = 0; s < 32; ++s) acc[s] = b2[o];
  {
    const float* wr = W2 + o * 64;
    for (int cb = 0; cb < 4; ++cb) {
      float w[16];
#pragma unroll
      for (int q = 0; q < 16; ++q) w[q] = wr[cb * 16 + q];
#pragma unroll
      for (int s = 0; s < 32; ++s) { FMA16(A + s * 64 + cb * 16); }
    }
  }
  __syncthreads();
#pragma unroll
  for (int s = 0; s < 32; ++s) A[s * 64 + o] = fmaxf(acc[s], 0.0f);
  __syncthreads();

  // ---- L3: 64 -> 128, fused relu + maxpool over s
  float* outp = out + 24576;
  for (int po = 0; po < 2; ++po) {
    int o2 = lane + (po << 6);
#pragma unroll
    for (int s = 0; s < 32; ++s) acc[s] = b3[o2];
    const float* wr = W3 + o2 * 64;
    for (int cb = 0; cb < 4; ++cb) {
      float w[16];
#pragma unroll
      for (int q = 0; q < 16; ++q) w[q] = wr[cb * 16 + q];
#pragma unroll
      for (int s = 0; s < 32; ++s) { FMA16(A + s * 64 + cb * 16); }
    }
    float mx = 0.0f;  // relu floor
#pragma unroll
    for (int s = 0; s < 32; ++s) mx = fmaxf(mx, acc[s]);
    outp[((size_t)b * 128 + o2) * 1024 + p] = mx;
  }
}

extern "C" void kernel_launch(void* const* d_in, const int* in_sizes, int n_in,
                              void* d_out, int out_size, void* d_ws, size_t ws_size,
                              hipStream_t stream) {
  const float* xyz = (const float*)d_in[0];
  const float* feats = (const float*)d_in[1];
  const float* W1 = (const float*)d_in[2];
  const float* b1 = (const float*)d_in[3];
  const float* W2 = (const float*)d_in[4];
  const float* b2 = (const float*)d_in[5];
  const float* W3 = (const float*)d_in[6];
  const float* b3 = (const float*)d_in[7];
  float* out = (float*)d_out;

  // ws layout (bytes):
  char* w = (char*)d_ws;
  int* idx = (int*)w;                              // 32 KB
  int* gidx = (int*)(w + 32768);                   // 1 MB
  unsigned* hist = (unsigned*)(w + 1081344);       // 16 KB (8*512)
  unsigned* starts = (unsigned*)(w + 1097728);     // 16 KB
  unsigned* rank = (unsigned*)(w + 1114112);       // 512 KB
  unsigned* cid = (unsigned*)(w + 1638400);        // 512 KB
  unsigned* oi2 = (unsigned*)(w + 2162688);        // 512 KB
  float* xs2 = (float*)(w + 2686976);              // 512 KB
  float* ys2 = (float*)(w + 3211264);              // 512 KB
  float* zs2 = (float*)(w + 3735552);              // 512 KB
  float* featsT = (float*)(w + 4259840);           // 32 MB (optional)
  size_t needT = 4259840 + (size_t)8 * 16384 * 64 * sizeof(float);
  int useT = (ws_size >= needT) ? 1 : 0;

  zero_hist<<<16, 256, 0, stream>>>(hist);
  hist_kernel<<<512, 256, 0, stream>>>(xyz, hist, rank, cid);
  scan_kernel<<<8, 512, 0, stream>>>(hist, starts);
  scatter_kernel<<<512, 256, 0, stream>>>(xyz, starts, rank, cid, xs2, ys2,
                                          zs2, oi2);
  fps_kernel<<<8, 1024, 131072, stream>>>(xyz, xs2, ys2, zs2, oi2, idx);
  gather_newxyz<<<32, 256, 0, stream>>>(xyz, idx, out);
  if (useT) transpose_feats<<<2048, 256, 0, stream>>>(feats, featsT);
  ballquery_kernel<<<2048, 256, 0, stream>>>(xyz, out, gidx);
  mlp_kernel<<<2048, 256, 0, stream>>>(xyz, feats, featsT, out, gidx,
                                       W1, b1, W2, b2, W3, b3, out, useT);
}

// Round 20
// 1998.892 us; speedup vs baseline: 1.4890x; 1.0357x over previous
//
#include <hip/hip_runtime.h>

// Problem constants: B=8, N=16384, NPOINT=1024, NSAMPLE=32, RADIUS=0.4, C_IN=64
#define R2 0.16f  // f32-nearest of python 0.4*0.4 (== nearest f32 to 0.16)

typedef float f32x2 __attribute__((ext_vector_type(2)));

// Exact (non-contracted) squared distance.
__device__ __forceinline__ float sqd(float x, float y, float z,
                                     float px, float py, float pz) {
  float dx = __fsub_rn(x, px);
  float dy = __fsub_rn(y, py);
  float dz = __fsub_rn(z, pz);
  return __fadd_rn(__fadd_rn(__fmul_rn(dx, dx), __fmul_rn(dy, dy)),
                   __fmul_rn(dz, dz));
}

// Canonical gfx9 wave64 reduce via DPP (verified R12-R18). Valid in lane 63.
__device__ __forceinline__ float wave64_max_dpp(float x) {
#define DPP_STEP(CTRL)                                                      \
  {                                                                         \
    int t_ = __builtin_amdgcn_update_dpp(__float_as_int(x),                 \
                                         __float_as_int(x), CTRL, 0xf, 0xf, \
                                         false);                            \
    x = fmaxf(x, __int_as_float(t_));                                       \
  }
  DPP_STEP(0x111) DPP_STEP(0x112) DPP_STEP(0x114)
  DPP_STEP(0x118) DPP_STEP(0x142) DPP_STEP(0x143)
#undef DPP_STEP
  return x;
}
__device__ __forceinline__ unsigned wave64_min_dpp_u32(unsigned x) {
#define DPP_STEP(CTRL)                                                      \
  {                                                                         \
    unsigned t_ = (unsigned)__builtin_amdgcn_update_dpp(                    \
        (int)x, (int)x, CTRL, 0xf, 0xf, false);                             \
    x = (t_ < x) ? t_ : x;                                                  \
  }
  DPP_STEP(0x111) DPP_STEP(0x112) DPP_STEP(0x114)
  DPP_STEP(0x118) DPP_STEP(0x142) DPP_STEP(0x143)
#undef DPP_STEP
  return x;
}

// ---------------- counting sort by 8x8x8 grid cell (per batch) ---------------
__global__ __launch_bounds__(256) void zero_hist(unsigned* __restrict__ h) {
  h[blockIdx.x * 256 + threadIdx.x] = 0u;  // grid 16 -> 4096 entries
}

__global__ __launch_bounds__(256) void hist_kernel(const float* __restrict__ xyz,
                                                   unsigned* __restrict__ hist,
                                                   unsigned* __restrict__ rank,
                                                   unsigned* __restrict__ cid) {
  int t = blockIdx.x * 256 + threadIdx.x;  // 0..131071 = (b,n)
  int b = t >> 14;
  const float* p = xyz + (size_t)t * 3;
  int cx = (int)floorf(p[0] + 4.0f);
  int cy = (int)floorf(p[1] + 4.0f);
  int cz = (int)floorf(p[2] + 4.0f);
  cx = min(max(cx, 0), 7);
  cy = min(max(cy, 0), 7);
  cz = min(max(cz, 0), 7);
  unsigned c = (unsigned)(cx | (cy << 3) | (cz << 6));
  unsigned r = atomicAdd(&hist[(b << 9) + c], 1u);
  rank[t] = r;
  cid[t] = c;
}

__global__ __launch_bounds__(512) void scan_kernel(const unsigned* __restrict__ hist,
                                                   unsigned* __restrict__ starts) {
  __shared__ unsigned a[512];
  int b = blockIdx.x, t = threadIdx.x;
  unsigned h = hist[(b << 9) + t];
  a[t] = h;
  __syncthreads();
  for (int s = 1; s < 512; s <<= 1) {
    unsigned v = (t >= s) ? a[t - s] : 0u;
    __syncthreads();
    a[t] += v;
    __syncthreads();
  }
  starts[(b << 9) + t] = a[t] - h;  // exclusive
}

__global__ __launch_bounds__(256) void scatter_kernel(
    const float* __restrict__ xyz, const unsigned* __restrict__ starts,
    const unsigned* __restrict__ rank, const unsigned* __restrict__ cid,
    float* __restrict__ xs2, float* __restrict__ ys2, float* __restrict__ zs2,
    unsigned* __restrict__ oi2) {
  int t = blockIdx.x * 256 + threadIdx.x;
  int b = t >> 14, n = t & 16383;
  unsigned pos = starts[(b << 9) + cid[t]] + rank[t];
  const float* p = xyz + (size_t)t * 3;
  size_t o = ((size_t)b << 14) + pos;
  xs2[o] = p[0];
  ys2[o] = p[1];
  zs2[o] = p[2];
  oi2[o] = (unsigned)n;
}

// ---------------- FPS (R18, unchanged — measured 1654 us) --------------------
__global__ __launch_bounds__(1024) void fps_kernel(
    const float* __restrict__ xyz, const float* __restrict__ xs,
    const float* __restrict__ ys, const float* __restrict__ zs,
    const unsigned* __restrict__ oi, int* __restrict__ idx_out) {
#pragma clang fp contract(off)
  extern __shared__ float4 xylds[];  // 8192 entries = 128 KB
  __shared__ unsigned long long s_gkey[3];
  __shared__ float s_cd[3][3][16];
  int b = blockIdx.x;
  int tid = threadIdx.x;
  int lane = tid & 63, wid = tid >> 6;
  const float* xb = xyz + (size_t)b * 16384 * 3;
  int base = tid << 4;  // 16 consecutive sorted slots
  const float4* xv = (const float4*)(xs + ((size_t)b << 14) + base);
  const float4* yv = (const float4*)(ys + ((size_t)b << 14) + base);
  const float4* zv = (const float4*)(zs + ((size_t)b << 14) + base);
  const uint4* ov = (const uint4*)(oi + ((size_t)b << 14) + base);
  float xr[16], yr[16], zr[16];
  unsigned OI[16];
#pragma unroll
  for (int q = 0; q < 4; ++q) {
    *(float4*)(xr + 4 * q) = xv[q];
    *(float4*)(yr + 4 * q) = yv[q];
    *(float4*)(zr + 4 * q) = zv[q];
    *(uint4*)(OI + 4 * q) = ov[q];
  }
  float bxl = xr[0], bxh = xr[0], byl = yr[0], byh = yr[0], bzl = zr[0],
        bzh = zr[0];
#pragma unroll
  for (int k = 1; k < 16; ++k) {
    bxl = fminf(bxl, xr[k]); bxh = fmaxf(bxh, xr[k]);
    byl = fminf(byl, yr[k]); byh = fmaxf(byh, yr[k]);
    bzl = fminf(bzl, zr[k]); bzh = fmaxf(bzh, zr[k]);
  }
  f32x2 Z[8], M[8];
#pragma unroll
  for (int q = 0; q < 8; ++q) {
    xylds[(q << 10) + tid] =
        make_float4(xr[2 * q], xr[2 * q + 1], yr[2 * q], yr[2 * q + 1]);
    Z[q] = {zr[2 * q], zr[2 * q + 1]};
    M[q] = {__builtin_inff(), __builtin_inff()};
  }
  if (tid == 0) idx_out[b * 1024] = 0;
  if (tid < 3) s_gkey[tid] = 0ull;
  __syncthreads();
  float px = xb[0], py = xb[1], pz = xb[2];
  float tv = __builtin_inff();  // invariant: tv == max(M)
  for (int it = 1; it < 1024; ++it) {
    int sl = it % 3;
    int slp2 = (sl + 2) % 3;
    float ddx = fmaxf(fmaxf(bxl - px, px - bxh), 0.0f);
    float ddy = fmaxf(fmaxf(byl - py, py - byh), 0.0f);
    float ddz = fmaxf(fmaxf(bzl - pz, pz - bzh), 0.0f);
    float lb = (ddx * ddx + ddy * ddy + ddz * ddz) * 0.999f;
    if (lb < tv) {
      f32x2 px2 = {px, px}, py2 = {py, py}, pz2 = {pz, pz};
      float ntv = -1.0f;
#pragma unroll
      for (int q = 0; q < 8; ++q) {
        float4 t = xylds[(q << 10) + tid];  // {x0,x1,y0,y1}
        f32x2 X = {t.x, t.y};
        f32x2 Y = {t.z, t.w};
        f32x2 dx = X - px2;
        f32x2 dy = Y - py2;
        f32x2 dz = Z[q] - pz2;
        f32x2 d = dx * dx + dy * dy + dz * dz;  // RN each op, ref order
        M[q].x = fminf(M[q].x, d.x);
        M[q].y = fminf(M[q].y, d.y);
        ntv = fmaxf(fmaxf(ntv, M[q].x), M[q].y);
      }
      tv = ntv;
    }
    float bv = wave64_max_dpp(tv);
    unsigned bvb = (unsigned)__builtin_amdgcn_readlane(__float_as_int(bv), 63);
    float bvf = __int_as_float((int)bvb);
    unsigned long long gk0 = __hip_atomic_load(
        &s_gkey[sl], __ATOMIC_RELAXED, __HIP_MEMORY_SCOPE_WORKGROUP);
    if (bvb >= (unsigned)(gk0 >> 18)) {  // wave might win -> rescan
      unsigned coi = 0xffffffffu;
      float wx = 0.0f, wy = 0.0f, wz = 0.0f;
      if (tv == bvf) {
#pragma unroll
        for (int q = 0; q < 8; ++q) {
          float4 t = xylds[(q << 10) + tid];
          if (M[q].x == bvf && OI[2 * q] < coi) {
            coi = OI[2 * q]; wx = t.x; wy = t.z; wz = Z[q].x;
          }
          if (M[q].y == bvf && OI[2 * q + 1] < coi) {
            coi = OI[2 * q + 1]; wx = t.y; wy = t.w; wz = Z[q].y;
          }
        }
      }
      unsigned woi = wave64_min_dpp_u32(coi);
      if (coi == woi && coi != 0xffffffffu) {  // unique lane (oi unique)
        s_cd[sl][0][wid] = wx;
        s_cd[sl][1][wid] = wy;
        s_cd[sl][2][wid] = wz;
        unsigned long long key = ((unsigned long long)bvb << 18) |
                                 ((unsigned long long)(16383u - woi) << 4) |
                                 (unsigned long long)wid;
        atomicMax(&s_gkey[sl], key);
      }
    }
    __syncthreads();  // the only barrier
    unsigned long long gk = s_gkey[sl];
    if (tid == 0) s_gkey[slp2] = 0ull;  // reset 2-ahead (epoch-safe)
    int w2 = (int)(gk & 15ull);
    int j = 16383 - (int)((gk >> 4) & 0x3fffull);
    px = s_cd[sl][0][w2];
    py = s_cd[sl][1][w2];
    pz = s_cd[sl][2][w2];
    if (tid == 0) idx_out[b * 1024 + it] = j;
  }
}

// ---------------- gather new_xyz into d_out[0 .. 24576) ----------------------
__global__ __launch_bounds__(256) void gather_newxyz(const float* __restrict__ xyz,
                                                     const int* __restrict__ idx,
                                                     float* __restrict__ out) {
  int t = blockIdx.x * 256 + threadIdx.x;  // 0..8191 = (b,p)
  int b = t >> 10;
  int i = idx[t];
  const float* src = xyz + ((size_t)b * 16384 + i) * 3;
  float* dst = out + (size_t)t * 3;
  dst[0] = src[0];
  dst[1] = src[1];
  dst[2] = src[2];
}

// ---------------- transpose features (B,64,N) -> (B,N,64) --------------------
__global__ __launch_bounds__(256) void transpose_feats(const float* __restrict__ f,
                                                       float* __restrict__ fT) {
  __shared__ float tile[64][65];
  int b = blockIdx.x >> 8;
  int n0 = (blockIdx.x & 255) << 6;
  int t = threadIdx.x;
  int nn = t & 63, c0 = t >> 6;
#pragma unroll
  for (int r = 0; r < 64; r += 4) {
    int c = c0 + r;
    tile[c][nn] = f[((size_t)b * 64 + c) * 16384 + n0 + nn];
  }
  __syncthreads();
  int cc = t & 63, n1 = t >> 6;
#pragma unroll
  for (int r = 0; r < 64; r += 4) {
    int n = n1 + r;
    fT[((size_t)b * 16384 + n0 + n) * 64 + cc] = tile[cc][n];
  }
}

// ---------------- ball query via grid cells + origidx bitmap -----------------
// Ball r=0.4 < cell size 1.0 -> candidate cells = cellof(c-0.4)..cellof(c+0.4)
// per axis (<=2 each, <=8 cells). The clamped cell map is monotone, so every
// in-ball point (incl. clamped outliers) lies in a candidate cell; the exact
// sqd test (bit-identical copies in xs2/ys2/zs2) filters. In-ball points'
// ORIGINAL indices are marked in a per-wave 16384-bit LDS bitmap (u32
// atomicOr); the 32 lowest set bits, extracted in ascending order (4 sweeps
// of u64 words: popc -> shfl_up prefix -> ctz walk), equal the reference's
// lax.top_k 32 smallest in-ball indices. Pad with first (= smallest).
// Deterministic regardless of the racy within-cell sort order.
__global__ __launch_bounds__(256) void ballquery_grid(
    const float* __restrict__ xs, const float* __restrict__ ys,
    const float* __restrict__ zs, const unsigned* __restrict__ oi,
    const unsigned* __restrict__ hist, const unsigned* __restrict__ starts,
    const float* __restrict__ newxyz, int* __restrict__ gidx) {
  __shared__ unsigned bm[4][512];
  __shared__ unsigned sfirst[4];
  int wid = threadIdx.x >> 6, lane = threadIdx.x & 63;
  int cid = blockIdx.x * 4 + wid;  // 0..8191
  int b = cid >> 10;
  float cx = newxyz[cid * 3 + 0];
  float cy = newxyz[cid * 3 + 1];
  float cz = newxyz[cid * 3 + 2];
  unsigned* mybm = bm[wid];
#pragma unroll
  for (int k = 0; k < 8; ++k) mybm[(k << 6) + lane] = 0u;
  // candidate cell ranges (same clamped monotone map as hist_kernel)
  int clox = min(max((int)floorf(cx - 0.4f + 4.0f), 0), 7);
  int chix = min(max((int)floorf(cx + 0.4f + 4.0f), 0), 7);
  int cloy = min(max((int)floorf(cy - 0.4f + 4.0f), 0), 7);
  int chiy = min(max((int)floorf(cy + 0.4f + 4.0f), 0), 7);
  int cloz = min(max((int)floorf(cz - 0.4f + 4.0f), 0), 7);
  int chiz = min(max((int)floorf(cz + 0.4f + 4.0f), 0), 7);
  const float* xsb = xs + ((size_t)b << 14);
  const float* ysb = ys + ((size_t)b << 14);
  const float* zsb = zs + ((size_t)b << 14);
  const unsigned* oib = oi + ((size_t)b << 14);
  const unsigned* hb = hist + (b << 9);
  const unsigned* sb = starts + (b << 9);
  for (int zz = cloz; zz <= chiz; ++zz)
    for (int yy = cloy; yy <= chiy; ++yy)
      for (int xx = clox; xx <= chix; ++xx) {
        unsigned cc = (unsigned)(xx | (yy << 3) | (zz << 6));
        unsigned st = sb[cc], cnt = hb[cc];
        for (unsigned c0 = 0; c0 < cnt; c0 += 64) {
          unsigned g = c0 + (unsigned)lane;
          if (g < cnt) {
            unsigned p = st + g;
            float d2 = sqd(xsb[p], ysb[p], zsb[p], cx, cy, cz);
            if (d2 <= R2) {
              unsigned o = oib[p];
              atomicOr(&mybm[o >> 5], 1u << (o & 31));
            }
          }
        }
      }
  // extraction: 4 sweeps; lane L covers u64 word w = s*64+L (= u32 2w, 2w+1)
  int* out = gidx + (size_t)cid * 32;
  unsigned running = 0;
  for (int s = 0; s < 4 && running < 32; ++s) {
    unsigned lo = mybm[(s << 7) + 2 * lane];
    unsigned hi = mybm[(s << 7) + 2 * lane + 1];
    unsigned long long W = ((unsigned long long)hi << 32) | lo;
    int c = __popcll(W);
    int incl = c;
#pragma unroll
    for (int d = 1; d < 64; d <<= 1) {
      int t = __shfl_up(incl, d);
      if (lane >= d) incl += t;
    }
    int total = __shfl(incl, 63);
    int basep = (int)running + incl - c;
    while (W != 0ull && basep < 32) {
      int t = (int)__builtin_ctzll(W);
      W &= W - 1ull;
      int idxv = (((s << 6) + lane) << 6) + t;
      if (basep == 0) sfirst[wid] = (unsigned)idxv;
      out[basep] = idxv;
      ++basep;
    }
    running += (unsigned)total;
  }
  unsigned nf = running < 32u ? running : 32u;
  unsigned first = sfirst[wid];
  for (unsigned s2 = nf + (unsigned)lane; s2 < 32u; s2 += 64u)
    out[s2] = (int)first;
}

// ---------------- fused group + MLP(67->64->64->128) + maxpool ---------------
#define FMA16(BASEPTR)                                                     \
  do {                                                                     \
    const float4* hp_ = (const float4*)(BASEPTR);                          \
    float4 v0 = hp_[0], v1 = hp_[1], v2 = hp_[2], v3 = hp_[3];             \
    float a = acc[s];                                                      \
    a = fmaf(w[0], v0.x, a);  a = fmaf(w[1], v0.y, a);                     \
    a = fmaf(w[2], v0.z, a);  a = fmaf(w[3], v0.w, a);                     \
    a = fmaf(w[4], v1.x, a);  a = fmaf(w[5], v1.y, a);                     \
    a = fmaf(w[6], v1.z, a);  a = fmaf(w[7], v1.w, a);                     \
    a = fmaf(w[8], v2.x, a);  a = fmaf(w[9], v2.y, a);                     \
    a = fmaf(w[10], v2.z, a); a = fmaf(w[11], v2.w, a);                    \
    a = fmaf(w[12], v3.x, a); a = fmaf(w[13], v3.y, a);                    \
    a = fmaf(w[14], v3.z, a); a = fmaf(w[15], v3.w, a);                    \
    acc[s] = a;                                                            \
  } while (0)

__global__ __launch_bounds__(256) void mlp_kernel(
    const float* __restrict__ xyz, const float* __restrict__ feats,
    const float* __restrict__ featsT, const float* __restrict__ newxyz,
    const int* __restrict__ gidx,
    const float* __restrict__ W1, const float* __restrict__ b1,
    const float* __restrict__ W2, const float* __restrict__ b2,
    const float* __restrict__ W3, const float* __restrict__ b3,
    float* __restrict__ out, int useT) {
  __shared__ float buf[4][32 * 68];
  int wid = threadIdx.x >> 6, lane = threadIdx.x & 63;
  int cid = blockIdx.x * 4 + wid;
  int b = cid >> 10, p = cid & 1023;
  float* A = buf[wid];
  const int* gi = gidx + (size_t)cid * 32;
  float cx = newxyz[cid * 3 + 0];
  float cy = newxyz[cid * 3 + 1];
  float cz = newxyz[cid * 3 + 2];

  // ---- stage h0
  if (useT) {
    const float4* fT4 = (const float4*)(featsT + (size_t)b * 16384 * 64);
    for (int t = lane; t < 512; t += 64) {
      int s = t >> 4, q = t & 15;
      int g = gi[s];
      float4 v = fT4[(size_t)g * 16 + q];
      *(float4*)(A + s * 68 + q * 4) = v;
    }
  } else {
    const float* fb = feats + (size_t)b * 64 * 16384;
    for (int t = lane; t < 2048; t += 64) {
      int c = t >> 5, s = t & 31;
      int g = gi[s];
      A[s * 68 + c] = fb[(size_t)c * 16384 + g];
    }
  }
  for (int t = lane; t < 96; t += 64) {
    int s = t / 3, c = t - s * 3;
    int g = gi[s];
    float pv = xyz[((size_t)b * 16384 + g) * 3 + c];
    float cv = (c == 0) ? cx : ((c == 1) ? cy : cz);
    A[s * 68 + 64 + c] = __fsub_rn(pv, cv);
  }
  if (lane < 32) A[lane * 68 + 67] = 0.0f;
  __syncthreads();

  int o = lane;
  float acc[32];

  // ---- L1: 67 -> 64
#pragma unroll
  for (int s = 0; s < 32; ++s) acc[s] = b1[o];
  {
    const float* wr = W1 + o * 67;
    for (int cb = 0; cb < 4; ++cb) {
      float w[16];
#pragma unroll
      for (int q = 0; q < 16; ++q) w[q] = wr[3 + cb * 16 + q];
#pragma unroll
      for (int s = 0; s < 32; ++s) { FMA16(A + s * 68 + cb * 16); }
    }
    float w0 = wr[0], w1 = wr[1], w2 = wr[2];
#pragma unroll
    for (int s = 0; s < 32; ++s) {
      float a = acc[s];
      a = fmaf(w0, A[s * 68 + 64], a);
      a = fmaf(w1, A[s * 68 + 65], a);
      a = fmaf(w2, A[s * 68 + 66], a);
      acc[s] = a;
    }
  }
  __syncthreads();
#pragma unroll
  for (int s = 0; s < 32; ++s) A[s * 64 + o] = fmaxf(acc[s], 0.0f);
  __syncthreads();

  // ---- L2: 64 -> 64
#pragma unroll
  for (int s = 0; s < 32; ++s) acc[s] = b2[o];
  {
    const float* wr = W2 + o * 64;
    for (int cb = 0; cb < 4; ++cb) {
      float w[16];
#pragma unroll
      for (int q = 0; q < 16; ++q) w[q] = wr[cb * 16 + q];
#pragma unroll
      for (int s = 0; s < 32; ++s) { FMA16(A + s * 64 + cb * 16); }
    }
  }
  __syncthreads();
#pragma unroll
  for (int s = 0; s < 32; ++s) A[s * 64 + o] = fmaxf(acc[s], 0.0f);
  __syncthreads();

  // ---- L3: 64 -> 128, fused relu + maxpool over s
  float* outp = out + 24576;
  for (int po = 0; po < 2; ++po) {
    int o2 = lane + (po << 6);
#pragma unroll
    for (int s = 0; s < 32; ++s) acc[s] = b3[o2];
    const float* wr = W3 + o2 * 64;
    for (int cb = 0; cb < 4; ++cb) {
      float w[16];
#pragma unroll
      for (int q = 0; q < 16; ++q) w[q] = wr[cb * 16 + q];
#pragma unroll
      for (int s = 0; s < 32; ++s) { FMA16(A + s * 64 + cb * 16); }
    }
    float mx = 0.0f;  // relu floor
#pragma unroll
    for (int s = 0; s < 32; ++s) mx = fmaxf(mx, acc[s]);
    outp[((size_t)b * 128 + o2) * 1024 + p] = mx;
  }
}

extern "C" void kernel_launch(void* const* d_in, const int* in_sizes, int n_in,
                              void* d_out, int out_size, void* d_ws, size_t ws_size,
                              hipStream_t stream) {
  const float* xyz = (const float*)d_in[0];
  const float* feats = (const float*)d_in[1];
  const float* W1 = (const float*)d_in[2];
  const float* b1 = (const float*)d_in[3];
  const float* W2 = (const float*)d_in[4];
  const float* b2 = (const float*)d_in[5];
  const float* W3 = (const float*)d_in[6];
  const float* b3 = (const float*)d_in[7];
  float* out = (float*)d_out;

  // ws layout (bytes):
  char* w = (char*)d_ws;
  int* idx = (int*)w;                              // 32 KB
  int* gidx = (int*)(w + 32768);                   // 1 MB
  unsigned* hist = (unsigned*)(w + 1081344);       // 16 KB (8*512)
  unsigned* starts = (unsigned*)(w + 1097728);     // 16 KB
  unsigned* rank = (unsigned*)(w + 1114112);       // 512 KB
  unsigned* cid = (unsigned*)(w + 1638400);        // 512 KB
  unsigned* oi2 = (unsigned*)(w + 2162688);        // 512 KB
  float* xs2 = (float*)(w + 2686976);              // 512 KB
  float* ys2 = (float*)(w + 3211264);              // 512 KB
  float* zs2 = (float*)(w + 3735552);              // 512 KB
  float* featsT = (float*)(w + 4259840);           // 32 MB (optional)
  size_t needT = 4259840 + (size_t)8 * 16384 * 64 * sizeof(float);
  int useT = (ws_size >= needT) ? 1 : 0;

  zero_hist<<<16, 256, 0, stream>>>(hist);
  hist_kernel<<<512, 256, 0, stream>>>(xyz, hist, rank, cid);
  scan_kernel<<<8, 512, 0, stream>>>(hist, starts);
  scatter_kernel<<<512, 256, 0, stream>>>(xyz, starts, rank, cid, xs2, ys2,
                                          zs2, oi2);
  fps_kernel<<<8, 1024, 131072, stream>>>(xyz, xs2, ys2, zs2, oi2, idx);
  gather_newxyz<<<32, 256, 0, stream>>>(xyz, idx, out);
  if (useT) transpose_feats<<<2048, 256, 0, stream>>>(feats, featsT);
  ballquery_grid<<<2048, 256, 0, stream>>>(xs2, ys2, zs2, oi2, hist, starts,
                                           out, gidx);
  mlp_kernel<<<2048, 256, 0, stream>>>(xyz, feats, featsT, out, gidx,
                                       W1, b1, W2, b2, W3, b3, out, useT);
}

// Round 23
// 1933.959 us; speedup vs baseline: 1.5390x; 1.0336x over previous
//
#include <hip/hip_runtime.h>

// Problem constants: B=8, N=16384, NPOINT=1024, NSAMPLE=32, RADIUS=0.4, C_IN=64
#define R2 0.16f  // f32-nearest of python 0.4*0.4 (== nearest f32 to 0.16)

typedef float f32x2 __attribute__((ext_vector_type(2)));

// Exact (non-contracted) squared distance.
__device__ __forceinline__ float sqd(float x, float y, float z,
                                     float px, float py, float pz) {
  float dx = __fsub_rn(x, px);
  float dy = __fsub_rn(y, py);
  float dz = __fsub_rn(z, pz);
  return __fadd_rn(__fadd_rn(__fmul_rn(dx, dx), __fmul_rn(dy, dy)),
                   __fmul_rn(dz, dz));
}

// Canonical gfx9 wave64 reduces via DPP (verified R12-R20). Valid in lane 63.
__device__ __forceinline__ float wave64_max_dpp(float x) {
#define DPP_STEP(CTRL)                                                      \
  {                                                                         \
    int t_ = __builtin_amdgcn_update_dpp(__float_as_int(x),                 \
                                         __float_as_int(x), CTRL, 0xf, 0xf, \
                                         false);                            \
    x = fmaxf(x, __int_as_float(t_));                                       \
  }
  DPP_STEP(0x111) DPP_STEP(0x112) DPP_STEP(0x114)
  DPP_STEP(0x118) DPP_STEP(0x142) DPP_STEP(0x143)
#undef DPP_STEP
  return x;
}
__device__ __forceinline__ float wave64_min_dpp_f32(float x) {
#define DPP_STEP(CTRL)                                                      \
  {                                                                         \
    int t_ = __builtin_amdgcn_update_dpp(__float_as_int(x),                 \
                                         __float_as_int(x), CTRL, 0xf, 0xf, \
                                         false);                            \
    x = fminf(x, __int_as_float(t_));                                       \
  }
  DPP_STEP(0x111) DPP_STEP(0x112) DPP_STEP(0x114)
  DPP_STEP(0x118) DPP_STEP(0x142) DPP_STEP(0x143)
#undef DPP_STEP
  return x;
}
__device__ __forceinline__ unsigned wave64_min_dpp_u32(unsigned x) {
#define DPP_STEP(CTRL)                                                      \
  {                                                                         \
    unsigned t_ = (unsigned)__builtin_amdgcn_update_dpp(                    \
        (int)x, (int)x, CTRL, 0xf, 0xf, false);                             \
    x = (t_ < x) ? t_ : x;                                                  \
  }
  DPP_STEP(0x111) DPP_STEP(0x112) DPP_STEP(0x114)
  DPP_STEP(0x118) DPP_STEP(0x142) DPP_STEP(0x143)
#undef DPP_STEP
  return x;
}

// ---------------- counting sort by 8x8x8 grid cell (per batch) ---------------
__global__ __launch_bounds__(256) void zero_hist(unsigned* __restrict__ h) {
  h[blockIdx.x * 256 + threadIdx.x] = 0u;  // grid 16 -> 4096 entries
}

__global__ __launch_bounds__(256) void hist_kernel(const float* __restrict__ xyz,
                                                   unsigned* __restrict__ hist,
                                                   unsigned* __restrict__ rank,
                                                   unsigned* __restrict__ cid) {
  int t = blockIdx.x * 256 + threadIdx.x;  // 0..131071 = (b,n)
  int b = t >> 14;
  const float* p = xyz + (size_t)t * 3;
  int cx = (int)floorf(p[0] + 4.0f);
  int cy = (int)floorf(p[1] + 4.0f);
  int cz = (int)floorf(p[2] + 4.0f);
  cx = min(max(cx, 0), 7);
  cy = min(max(cy, 0), 7);
  cz = min(max(cz, 0), 7);
  unsigned c = (unsigned)(cx | (cy << 3) | (cz << 6));
  unsigned r = atomicAdd(&hist[(b << 9) + c], 1u);
  rank[t] = r;
  cid[t] = c;
}

__global__ __launch_bounds__(512) void scan_kernel(const unsigned* __restrict__ hist,
                                                   unsigned* __restrict__ starts) {
  __shared__ unsigned a[512];
  int b = blockIdx.x, t = threadIdx.x;
  unsigned h = hist[(b << 9) + t];
  a[t] = h;
  __syncthreads();
  for (int s = 1; s < 512; s <<= 1) {
    unsigned v = (t >= s) ? a[t - s] : 0u;
    __syncthreads();
    a[t] += v;
    __syncthreads();
  }
  starts[(b << 9) + t] = a[t] - h;  // exclusive
}

__global__ __launch_bounds__(256) void scatter_kernel(
    const float* __restrict__ xyz, const unsigned* __restrict__ starts,
    const unsigned* __restrict__ rank, const unsigned* __restrict__ cid,
    float* __restrict__ xs2, float* __restrict__ ys2, float* __restrict__ zs2,
    unsigned* __restrict__ oi2) {
  int t = blockIdx.x * 256 + threadIdx.x;
  int b = t >> 14, n = t & 16383;
  unsigned pos = starts[(b << 9) + cid[t]] + rank[t];
  const float* p = xyz + (size_t)t * 3;
  size_t o = ((size_t)b << 14) + pos;
  xs2[o] = p[0];
  ys2[o] = p[1];
  zs2[o] = p[2];
  oi2[o] = (unsigned)n;
}

// ---------------- FPS + fused transpose (heterogeneous blocks) ---------------
// blocks 0-7: FPS, one block per batch, 16 SORTED pts/thread, R18 protocol +
//   NEW wave-uniform skip: wave union-bbox (DPP+readlane at init); per iter,
//   if wave_lb*0.999 >= bv_prev -> skip per-thread test, sweep AND the DPP max
//   (tv unchanged for all lanes => bv provably unchanged — bit-exact; chain:
//   d2 >= thread_lb >= wave_lb >= bv_prev >= bv_cur >= tv, tv monotone).
//   Else: exact old path (per-thread bbox refine + masked sweep + DPP max).
//   The sweep SET is preserved exactly. Also: %3 -> conditional rotation, and
//   tid0 writes new_xyz directly (winner coords live in regs) — gather kernel
//   eliminated.
// blocks 8+: feats transpose (4 sub-tiles of 64x64 per 1024-thr block, tile
//   buffers carved from the dynamic-LDS block) — runs on the 248 idle CUs,
//   fully hidden under FPS. No data dependence with FPS.
__global__ __launch_bounds__(1024) void fps_kernel(
    const float* __restrict__ xyz, const float* __restrict__ xs,
    const float* __restrict__ ys, const float* __restrict__ zs,
    const unsigned* __restrict__ oi, int* __restrict__ idx_out,
    float* __restrict__ newxyz_out, const float* __restrict__ feats,
    float* __restrict__ featsT) {
#pragma clang fp contract(off)
  extern __shared__ float4 xylds[];  // 8192 float4 = 128 KB
  __shared__ unsigned long long s_gkey[3];
  __shared__ float s_cd[3][3][16];
  int tid = threadIdx.x;
  if (blockIdx.x >= 8) {
    // ---------------- transpose role ----------------
    int sub = tid >> 8, t = tid & 255;
    int tileid = (blockIdx.x - 8) * 4 + sub;  // 0..2047
    int b = tileid >> 8;
    int n0 = (tileid & 255) << 6;
    float* tile = ((float*)xylds) + sub * 4160;  // 64*65 floats each
    int nn = t & 63, c0 = t >> 6;
#pragma unroll
    for (int r = 0; r < 64; r += 4) {
      int c = c0 + r;
      tile[c * 65 + nn] = feats[((size_t)b * 64 + c) * 16384 + n0 + nn];
    }
    __syncthreads();
    int cc = t & 63, n1 = t >> 6;
#pragma unroll
    for (int r = 0; r < 64; r += 4) {
      int n = n1 + r;
      featsT[((size_t)b * 16384 + n0 + n) * 64 + cc] = tile[cc * 65 + n];
    }
    return;
  }
  // ---------------- FPS role ----------------
  int b = blockIdx.x;
  int lane = tid & 63, wid = tid >> 6;
  const float* xb = xyz + (size_t)b * 16384 * 3;
  int base = tid << 4;  // 16 consecutive sorted slots
  const float4* xv = (const float4*)(xs + ((size_t)b << 14) + base);
  const float4* yv = (const float4*)(ys + ((size_t)b << 14) + base);
  const float4* zv = (const float4*)(zs + ((size_t)b << 14) + base);
  const uint4* ov = (const uint4*)(oi + ((size_t)b << 14) + base);
  float xr[16], yr[16], zr[16];
  unsigned OI[16];
#pragma unroll
  for (int q = 0; q < 4; ++q) {
    *(float4*)(xr + 4 * q) = xv[q];
    *(float4*)(yr + 4 * q) = yv[q];
    *(float4*)(zr + 4 * q) = zv[q];
    *(uint4*)(OI + 4 * q) = ov[q];
  }
  // per-thread bbox of its 16 points
  float bxl = xr[0], bxh = xr[0], byl = yr[0], byh = yr[0], bzl = zr[0],
        bzh = zr[0];
#pragma unroll
  for (int k = 1; k < 16; ++k) {
    bxl = fminf(bxl, xr[k]); bxh = fmaxf(bxh, xr[k]);
    byl = fminf(byl, yr[k]); byh = fmaxf(byh, yr[k]);
    bzl = fminf(bzl, zr[k]); bzh = fmaxf(bzh, zr[k]);
  }
  // wave union bbox, broadcast to all lanes via readlane(63)
  float wbxl = __int_as_float(
      __builtin_amdgcn_readlane(__float_as_int(wave64_min_dpp_f32(bxl)), 63));
  float wbxh = __int_as_float(
      __builtin_amdgcn_readlane(__float_as_int(wave64_max_dpp(bxh)), 63));
  float wbyl = __int_as_float(
      __builtin_amdgcn_readlane(__float_as_int(wave64_min_dpp_f32(byl)), 63));
  float wbyh = __int_as_float(
      __builtin_amdgcn_readlane(__float_as_int(wave64_max_dpp(byh)), 63));
  float wbzl = __int_as_float(
      __builtin_amdgcn_readlane(__float_as_int(wave64_min_dpp_f32(bzl)), 63));
  float wbzh = __int_as_float(
      __builtin_amdgcn_readlane(__float_as_int(wave64_max_dpp(bzh)), 63));
  f32x2 Z[8], M[8];
#pragma unroll
  for (int q = 0; q < 8; ++q) {
    xylds[(q << 10) + tid] =
        make_float4(xr[2 * q], xr[2 * q + 1], yr[2 * q], yr[2 * q + 1]);
    Z[q] = {zr[2 * q], zr[2 * q + 1]};
    M[q] = {__builtin_inff(), __builtin_inff()};
  }
  if (tid == 0) {
    idx_out[b * 1024] = 0;
    float* o0 = newxyz_out + (size_t)b * 1024 * 3;
    o0[0] = xb[0]; o0[1] = xb[1]; o0[2] = xb[2];
  }
  if (tid < 3) s_gkey[tid] = 0ull;
  __syncthreads();
  float px = xb[0], py = xb[1], pz = xb[2];
  float tv = __builtin_inff();   // invariant: tv == max(M)
  float bvf = __builtin_inff();  // wave max of tv (valid from prev iter)
  unsigned bvb = 0x7f800000u;    // bits of bvf
  int sl = 1, slp2 = 0;
  for (int it = 1; it < 1024; ++it) {
    // ---- wave-uniform skip pre-check (uniform branch)
    float wdx = fmaxf(fmaxf(wbxl - px, px - wbxh), 0.0f);
    float wdy = fmaxf(fmaxf(wbyl - py, py - wbyh), 0.0f);
    float wdz = fmaxf(fmaxf(wbzl - pz, pz - wbzh), 0.0f);
    float wlb = (wdx * wdx + wdy * wdy + wdz * wdz) * 0.999f;
    if (wlb < bvf) {
      // per-thread bbox refine (exact old criterion)
      float ddx = fmaxf(fmaxf(bxl - px, px - bxh), 0.0f);
      float ddy = fmaxf(fmaxf(byl - py, py - byh), 0.0f);
      float ddz = fmaxf(fmaxf(bzl - pz, pz - bzh), 0.0f);
      float lb = (ddx * ddx + ddy * ddy + ddz * ddz) * 0.999f;
      if (lb < tv) {
        f32x2 px2 = {px, px}, py2 = {py, py}, pz2 = {pz, pz};
        float ntv = -1.0f;
#pragma unroll
        for (int q = 0; q < 8; ++q) {
          float4 t = xylds[(q << 10) + tid];  // {x0,x1,y0,y1}
          f32x2 X = {t.x, t.y};
          f32x2 Y = {t.z, t.w};
          f32x2 dx = X - px2;
          f32x2 dy = Y - py2;
          f32x2 dz = Z[q] - pz2;
          f32x2 d = dx * dx + dy * dy + dz * dz;  // RN each op, ref order
          M[q].x = fminf(M[q].x, d.x);
          M[q].y = fminf(M[q].y, d.y);
          ntv = fmaxf(fmaxf(ntv, M[q].x), M[q].y);
        }
        tv = ntv;
      }
      float bv = wave64_max_dpp(tv);
      bvb = (unsigned)__builtin_amdgcn_readlane(__float_as_int(bv), 63);
      bvf = __int_as_float((int)bvb);
    }
    // else: no lane changed tv -> bvb/bvf carry over (bit-exact)
    unsigned long long gk0 = __hip_atomic_load(
        &s_gkey[sl], __ATOMIC_RELAXED, __HIP_MEMORY_SCOPE_WORKGROUP);
    if (bvb >= (unsigned)(gk0 >> 18)) {  // wave might win -> rescan
      unsigned coi = 0xffffffffu;
      float wx = 0.0f, wy = 0.0f, wz = 0.0f;
      if (tv == bvf) {
#pragma unroll
        for (int q = 0; q < 8; ++q) {
          float4 t = xylds[(q << 10) + tid];
          if (M[q].x == bvf && OI[2 * q] < coi) {
            coi = OI[2 * q]; wx = t.x; wy = t.z; wz = Z[q].x;
          }
          if (M[q].y == bvf && OI[2 * q + 1] < coi) {
            coi = OI[2 * q + 1]; wx = t.y; wy = t.w; wz = Z[q].y;
          }
        }
      }
      unsigned woi = wave64_min_dpp_u32(coi);
      if (coi == woi && coi != 0xffffffffu) {  // unique lane (oi unique)
        s_cd[sl][0][wid] = wx;
        s_cd[sl][1][wid] = wy;
        s_cd[sl][2][wid] = wz;
        unsigned long long key = ((unsigned long long)bvb << 18) |
                                 ((unsigned long long)(16383u - woi) << 4) |
                                 (unsigned long long)wid;
        atomicMax(&s_gkey[sl], key);
      }
    }
    __syncthreads();  // the only barrier
    unsigned long long gk = s_gkey[sl];
    if (tid == 0) s_gkey[slp2] = 0ull;  // reset 2-ahead (epoch-safe)
    int w2 = (int)(gk & 15ull);
    int j = 16383 - (int)((gk >> 4) & 0x3fffull);
    px = s_cd[sl][0][w2];
    py = s_cd[sl][1][w2];
    pz = s_cd[sl][2][w2];
    if (tid == 0) {
      idx_out[b * 1024 + it] = j;
      float* o = newxyz_out + ((size_t)b * 1024 + it) * 3;
      o[0] = px; o[1] = py; o[2] = pz;
    }
    sl = (sl == 2) ? 0 : sl + 1;
    slp2 = (slp2 == 2) ? 0 : slp2 + 1;
  }
}

// ---------------- ball query via grid cells + origidx bitmap -----------------
__global__ __launch_bounds__(256) void ballquery_grid(
    const float* __restrict__ xs, const float* __restrict__ ys,
    const float* __restrict__ zs, const unsigned* __restrict__ oi,
    const unsigned* __restrict__ hist, const unsigned* __restrict__ starts,
    const float* __restrict__ newxyz, int* __restrict__ gidx) {
  __shared__ unsigned bm[4][512];
  __shared__ unsigned sfirst[4];
  int wid = threadIdx.x >> 6, lane = threadIdx.x & 63;
  int cid = blockIdx.x * 4 + wid;  // 0..8191
  int b = cid >> 10;
  float cx = newxyz[cid * 3 + 0];
  float cy = newxyz[cid * 3 + 1];
  float cz = newxyz[cid * 3 + 2];
  unsigned* mybm = bm[wid];
#pragma unroll
  for (int k = 0; k < 8; ++k) mybm[(k << 6) + lane] = 0u;
  int clox = min(max((int)floorf(cx - 0.4f + 4.0f), 0), 7);
  int chix = min(max((int)floorf(cx + 0.4f + 4.0f), 0), 7);
  int cloy = min(max((int)floorf(cy - 0.4f + 4.0f), 0), 7);
  int chiy = min(max((int)floorf(cy + 0.4f + 4.0f), 0), 7);
  int cloz = min(max((int)floorf(cz - 0.4f + 4.0f), 0), 7);
  int chiz = min(max((int)floorf(cz + 0.4f + 4.0f), 0), 7);
  const float* xsb = xs + ((size_t)b << 14);
  const float* ysb = ys + ((size_t)b << 14);
  const float* zsb = zs + ((size_t)b << 14);
  const unsigned* oib = oi + ((size_t)b << 14);
  const unsigned* hb = hist + (b << 9);
  const unsigned* sb = starts + (b << 9);
  for (int zz = cloz; zz <= chiz; ++zz)
    for (int yy = cloy; yy <= chiy; ++yy)
      for (int xx = clox; xx <= chix; ++xx) {
        unsigned cc = (unsigned)(xx | (yy << 3) | (zz << 6));
        unsigned st = sb[cc], cnt = hb[cc];
        for (unsigned c0 = 0; c0 < cnt; c0 += 64) {
          unsigned g = c0 + (unsigned)lane;
          if (g < cnt) {
            unsigned p = st + g;
            float d2 = sqd(xsb[p], ysb[p], zsb[p], cx, cy, cz);
            if (d2 <= R2) {
              unsigned o = oib[p];
              atomicOr(&mybm[o >> 5], 1u << (o & 31));
            }
          }
        }
      }
  // extraction: 4 sweeps; lane L covers u64 word w = s*64+L
  int* out = gidx + (size_t)cid * 32;
  unsigned running = 0;
  for (int s = 0; s < 4 && running < 32; ++s) {
    unsigned lo = mybm[(s << 7) + 2 * lane];
    unsigned hi = mybm[(s << 7) + 2 * lane + 1];
    unsigned long long W = ((unsigned long long)hi << 32) | lo;
    int c = __popcll(W);
    int incl = c;
#pragma unroll
    for (int d = 1; d < 64; d <<= 1) {
      int t = __shfl_up(incl, d);
      if (lane >= d) incl += t;
    }
    int total = __shfl(incl, 63);
    int basep = (int)running + incl - c;
    while (W != 0ull && basep < 32) {
      int t = (int)__builtin_ctzll(W);
      W &= W - 1ull;
      int idxv = (((s << 6) + lane) << 6) + t;
      if (basep == 0) sfirst[wid] = (unsigned)idxv;
      out[basep] = idxv;
      ++basep;
    }
    running += (unsigned)total;
  }
  unsigned nf = running < 32u ? running : 32u;
  unsigned first = sfirst[wid];
  for (unsigned s2 = nf + (unsigned)lane; s2 < 32u; s2 += 64u)
    out[s2] = (int)first;
}

// ---------------- fused group + MLP(67->64->64->128) + maxpool ---------------
#define FMA16(BASEPTR)                                                     \
  do {                                                                     \
    const float4* hp_ = (const float4*)(BASEPTR);                          \
    float4 v0 = hp_[0], v1 = hp_[1], v2 = hp_[2], v3 = hp_[3];             \
    float a = acc[s];                                                      \
    a = fmaf(w[0], v0.x, a);  a = fmaf(w[1], v0.y, a);                     \
    a = fmaf(w[2], v0.z, a);  a = fmaf(w[3], v0.w, a);                     \
    a = fmaf(w[4], v1.x, a);  a = fmaf(w[5], v1.y, a);                     \
    a = fmaf(w[6], v1.z, a);  a = fmaf(w[7], v1.w, a);                     \
    a = fmaf(w[8], v2.x, a);  a = fmaf(w[9], v2.y, a);                     \
    a = fmaf(w[10], v2.z, a); a = fmaf(w[11], v2.w, a);                    \
    a = fmaf(w[12], v3.x, a); a = fmaf(w[13], v3.y, a);                    \
    a = fmaf(w[14], v3.z, a); a = fmaf(w[15], v3.w, a);                    \
    acc[s] = a;                                                            \
  } while (0)

__global__ __launch_bounds__(256) void mlp_kernel(
    const float* __restrict__ xyz, const float* __restrict__ feats,
    const float* __restrict__ featsT, const float* __restrict__ newxyz,
    const int* __restrict__ gidx,
    const float* __restrict__ W1, const float* __restrict__ b1,
    const float* __restrict__ W2, const float* __restrict__ b2,
    const float* __restrict__ W3, const float* __restrict__ b3,
    float* __restrict__ out, int useT) {
  __shared__ float buf[4][32 * 68];
  int wid = threadIdx.x >> 6, lane = threadIdx.x & 63;
  int cid = blockIdx.x * 4 + wid;
  int b = cid >> 10, p = cid & 1023;
  float* A = buf[wid];
  const int* gi = gidx + (size_t)cid * 32;
  float cx = newxyz[cid * 3 + 0];
  float cy = newxyz[cid * 3 + 1];
  float cz = newxyz[cid * 3 + 2];

  // ---- stage h0
  if (useT) {
    const float4* fT4 = (const float4*)(featsT + (size_t)b * 16384 * 64);
    for (int t = lane; t < 512; t += 64) {
      int s = t >> 4, q = t & 15;
      int g = gi[s];
      float4 v = fT4[(size_t)g * 16 + q];
      *(float4*)(A + s * 68 + q * 4) = v;
    }
  } else {
    const float* fb = feats + (size_t)b * 64 * 16384;
    for (int t = lane; t < 2048; t += 64) {
      int c = t >> 5, s = t & 31;
      int g = gi[s];
      A[s * 68 + c] = fb[(size_t)c * 16384 + g];
    }
  }
  for (int t = lane; t < 96; t += 64) {
    int s = t / 3, c = t - s * 3;
    int g = gi[s];
    float pv = xyz[((size_t)b * 16384 + g) * 3 + c];
    float cv = (c == 0) ? cx : ((c == 1) ? cy : cz);
    A[s * 68 + 64 + c] = __fsub_rn(pv, cv);
  }
  if (lane < 32) A[lane * 68 + 67] = 0.0f;
  __syncthreads();

  int o = lane;
  float acc[32];

  // ---- L1: 67 -> 64
#pragma unroll
  for (int s = 0; s < 32; ++s) acc[s] = b1[o];
  {
    const float* wr = W1 + o * 67;
    for (int cb = 0; cb < 4; ++cb) {
      float w[16];
#pragma unroll
      for (int q = 0; q < 16; ++q) w[q] = wr[3 + cb * 16 + q];
#pragma unroll
      for (int s = 0; s < 32; ++s) { FMA16(A + s * 68 + cb * 16); }
    }
    float w0 = wr[0], w1 = wr[1], w2 = wr[2];
#pragma unroll
    for (int s = 0; s < 32; ++s) {
      float a = acc[s];
      a = fmaf(w0, A[s * 68 + 64], a);
      a = fmaf(w1, A[s * 68 + 65], a);
      a = fmaf(w2, A[s * 68 + 66], a);
      acc[s] = a;
    }
  }
  __syncthreads();
#pragma unroll
  for (int s = 0; s < 32; ++s) A[s * 64 + o] = fmaxf(acc[s], 0.0f);
  __syncthreads();

  // ---- L2: 64 -> 64
#pragma unroll
  for (int s = 0; s < 32; ++s) acc[s] = b2[o];
  {
    const float* wr = W2 + o * 64;
    for (int cb = 0; cb < 4; ++cb) {
      float w[16];
#pragma unroll
      for (int q = 0; q < 16; ++q) w[q] = wr[cb * 16 + q];
#pragma unroll
      for (int s = 0; s < 32; ++s) { FMA16(A + s * 64 + cb * 16); }
    }
  }
  __syncthreads();
#pragma unroll
  for (int s = 0; s < 32; ++s) A[s * 64 + o] = fmaxf(acc[s], 0.0f);
  __syncthreads();

  // ---- L3: 64 -> 128, fused relu + maxpool over s
  float* outp = out + 24576;
  for (int po = 0; po < 2; ++po) {
    int o2 = lane + (po << 6);
#pragma unroll
    for (int s = 0; s < 32; ++s) acc[s] = b3[o2];
    const float* wr = W3 + o2 * 64;
    for (int cb = 0; cb < 4; ++cb) {
      float w[16];
#pragma unroll
      for (int q = 0; q < 16; ++q) w[q] = wr[cb * 16 + q];
#pragma unroll
      for (int s = 0; s < 32; ++s) { FMA16(A + s * 64 + cb * 16); }
    }
    float mx = 0.0f;  // relu floor
#pragma unroll
    for (int s = 0; s < 32; ++s) mx = fmaxf(mx, acc[s]);
    outp[((size_t)b * 128 + o2) * 1024 + p] = mx;
  }
}

extern "C" void kernel_launch(void* const* d_in, const int* in_sizes, int n_in,
                              void* d_out, int out_size, void* d_ws, size_t ws_size,
                              hipStream_t stream) {
  const float* xyz = (const float*)d_in[0];
  const float* feats = (const float*)d_in[1];
  const float* W1 = (const float*)d_in[2];
  const float* b1 = (const float*)d_in[3];
  const float* W2 = (const float*)d_in[4];
  const float* b2 = (const float*)d_in[5];
  const float* W3 = (const float*)d_in[6];
  const float* b3 = (const float*)d_in[7];
  float* out = (float*)d_out;

  // ws layout (bytes):
  char* w = (char*)d_ws;
  int* idx = (int*)w;                              // 32 KB
  int* gidx = (int*)(w + 32768);                   // 1 MB
  unsigned* hist = (unsigned*)(w + 1081344);       // 16 KB (8*512)
  unsigned* starts = (unsigned*)(w + 1097728);     // 16 KB
  unsigned* rank = (unsigned*)(w + 1114112);       // 512 KB
  unsigned* cid = (unsigned*)(w + 1638400);        // 512 KB
  unsigned* oi2 = (unsigned*)(w + 2162688);        // 512 KB
  float* xs2 = (float*)(w + 2686976);              // 512 KB
  float* ys2 = (float*)(w + 3211264);              // 512 KB
  float* zs2 = (float*)(w + 3735552);              // 512 KB
  float* featsT = (float*)(w + 4259840);           // 32 MB (optional)
  size_t needT = 4259840 + (size_t)8 * 16384 * 64 * sizeof(float);
  int useT = (ws_size >= needT) ? 1 : 0;

  zero_hist<<<16, 256, 0, stream>>>(hist);
  hist_kernel<<<512, 256, 0, stream>>>(xyz, hist, rank, cid);
  scan_kernel<<<8, 512, 0, stream>>>(hist, starts);
  scatter_kernel<<<512, 256, 0, stream>>>(xyz, starts, rank, cid, xs2, ys2,
                                          zs2, oi2);
  fps_kernel<<<useT ? 520 : 8, 1024, 131072, stream>>>(
      xyz, xs2, ys2, zs2, oi2, idx, out, feats, featsT);
  ballquery_grid<<<2048, 256, 0, stream>>>(xs2, ys2, zs2, oi2, hist, starts,
                                           out, gidx);
  mlp_kernel<<<2048, 256, 0, stream>>>(xyz, feats, featsT, out, gidx,
                                       W1, b1, W2, b2, W3, b3, out, useT);
}